// Round 4
// baseline (346.197 us; speedup 1.0000x reference)
//
#include <hip/hip_runtime.h>
#include <cmath>

// Fused Fourier-MLP, single self-contained kernel (no d_ws, no prep kernel —
// R3's two-kernel d_ws producer/consumer failed the post-timing re-poison
// tripwire; everything else was validated).
// Numerics: activations split f32 -> f16 hi+lo (A-side), weights rounded to
// f16 (B-side hi only). Products Ah*Bh + Al*Bh, fp32 accum, bias as C-init.
// Per-wave private LDS tile [32][64] f32, XOR swizzle on 16B granules
// (phys = logical ^ (row&15)); 0 bank conflicts measured in R2/R3.
// Trig: sincosf(pi*x) seed + 7 double-angle steps per channel.

typedef _Float16 half8 __attribute__((ext_vector_type(8)));
typedef float float4v __attribute__((ext_vector_type(4)));

#define PI_F 3.14159265358979323846f

__device__ __forceinline__ float4v mfma16(half8 a, half8 b, float4v c) {
    return __builtin_amdgcn_mfma_f32_16x16x32_f16(a, b, c, 0, 0, 0);
}

// MODE 0: first layer, W row-stride 51, predicated k<51 (scalar loads, L1-hot)
// MODE 1: hidden 64x64 dense (vectorized float4 loads, L1-hot)
// MODE 2: last layer, W3 [4][64]: jch = l15 < 4 predicated, NT = 1, global out
template <int MODE, int NT, bool RELU>
__device__ __forceinline__ void mlp_layer(const float* __restrict__ W,
                                          const float* __restrict__ bias,
                                          float* __restrict__ hb,
                                          float* __restrict__ outp,
                                          long long wbase, int lane, long long n)
{
    const int l15 = lane & 15;
    const int g   = lane >> 4;

    // ---- A-phase: activations from LDS, split f32 -> f16 hi/lo.
    // Fragment mapping (HW-verified R2): slot j, group g, chunk c <-> k = 32c+8g+j.
    half8 Ah[2][2], Al[2][2];
#pragma unroll
    for (int mt = 0; mt < 2; ++mt) {
        const int row = 16 * mt + l15;
#pragma unroll
        for (int c = 0; c < 2; ++c) {
            const int gl = 8 * c + 2 * g;                  // logical 16B granule
            float4v r0 = *(const float4v*)&hb[row * 64 + ((gl ^ l15) << 2)];
            float4v r1 = *(const float4v*)&hb[row * 64 + (((gl + 1) ^ l15) << 2)];
#pragma unroll
            for (int j = 0; j < 4; ++j) {
                float v0 = r0[j]; _Float16 h0 = (_Float16)v0;
                Ah[mt][c][j] = h0; Al[mt][c][j] = (_Float16)(v0 - (float)h0);
                float v1 = r1[j]; _Float16 h1 = (_Float16)v1;
                Ah[mt][c][4 + j] = h1; Al[mt][c][4 + j] = (_Float16)(v1 - (float)h1);
            }
        }
    }

#pragma unroll
    for (int nt = 0; nt < NT; ++nt) {
        const int jch = 16 * nt + l15;
        float bj;
        if constexpr (MODE == 2) bj = (l15 < 4) ? bias[l15] : 0.0f;
        else                     bj = bias[jch];

        // ---- B-phase: weights -> f16 (hi only; lo term dropped, err ~2e-3)
        half8 Bh[2];
#pragma unroll
        for (int c = 0; c < 2; ++c) {
            if constexpr (MODE == 0) {
#pragma unroll
                for (int jj = 0; jj < 8; ++jj) {
                    const int k = 32 * c + 8 * g + jj;
                    const float w = (k < 51) ? W[jch * 51 + k] : 0.0f;
                    Bh[c][jj] = (_Float16)w;
                }
            } else if constexpr (MODE == 1) {
                const float4v* Wv = (const float4v*)(W + jch * 64 + 32 * c + 8 * g);
                float4v w0 = Wv[0], w1 = Wv[1];
#pragma unroll
                for (int jj = 0; jj < 4; ++jj) {
                    Bh[c][jj]     = (_Float16)w0[jj];
                    Bh[c][4 + jj] = (_Float16)w1[jj];
                }
            } else {                                        // MODE 2: W3 [4][64]
                if (l15 < 4) {
                    const float4v* Wv = (const float4v*)(W + l15 * 64 + 32 * c + 8 * g);
                    float4v w0 = Wv[0], w1 = Wv[1];
#pragma unroll
                    for (int jj = 0; jj < 4; ++jj) {
                        Bh[c][jj]     = (_Float16)w0[jj];
                        Bh[c][4 + jj] = (_Float16)w1[jj];
                    }
                } else {
#pragma unroll
                    for (int jj = 0; jj < 8; ++jj) Bh[c][jj] = (_Float16)0.0f;
                }
            }
        }

#pragma unroll
        for (int mt = 0; mt < 2; ++mt) {
            float4v acc = {bj, bj, bj, bj};
#pragma unroll
            for (int c = 0; c < 2; ++c) {
                acc = mfma16(Ah[mt][c], Bh[c], acc);
                acc = mfma16(Al[mt][c], Bh[c], acc);
            }
            // C-layout: col = l15, rows = 16mt + 4g + r  (HW-verified R2)
            if constexpr (MODE == 2) {
                if (l15 < 4) {
#pragma unroll
                    for (int r = 0; r < 4; ++r) {
                        long long p = wbase + 16 * mt + 4 * g + r;
                        if (p < n) outp[p * 4 + l15] = acc[r];
                    }
                }
            } else {
#pragma unroll
                for (int r = 0; r < 4; ++r) {
                    float v = acc[r];
                    if (RELU) v = fmaxf(v, 0.0f);
                    const int row = 16 * mt + 4 * g + r;
                    const int phys = (jch >> 2) ^ (row & 15);
                    hb[row * 64 + (phys << 2) + (jch & 3)] = v;
                }
            }
        }
    }
}

__global__ __launch_bounds__(256, 4)
void fused_mlp_r4(const float* __restrict__ x,
                  const float* __restrict__ W0, const float* __restrict__ b0,
                  const float* __restrict__ W1, const float* __restrict__ b1,
                  const float* __restrict__ W2, const float* __restrict__ b2,
                  const float* __restrict__ W3, const float* __restrict__ b3,
                  float* __restrict__ out, long long n)
{
    __shared__ float hbuf[4][32 * 64];                     // 32 KB, 8 KB/wave
    const int tid  = threadIdx.x;
    const int wave = tid >> 6;
    const int lane = tid & 63;
    float* hb = hbuf[wave];

    const long long wbase = (long long)blockIdx.x * 128 + wave * 32;

    // ---- encoding: lane pair (l, l+32) both compute point (wbase + (l&31));
    //      group 0 writes granules 0..7 (cols 0..31), group 1 writes 8..15.
    {
        long long p = wbase + (lane & 31);
        if (p > n - 1) p = n - 1;
        const float xc[3] = {x[3 * p + 0], x[3 * p + 1], x[3 * p + 2]};

        float s[3][8], c[3][8];
#pragma unroll
        for (int ch = 0; ch < 3; ++ch) {
            sincosf(PI_F * xc[ch], &s[ch][0], &c[ch][0]);   // seed (arg <= pi)
#pragma unroll
            for (int f = 1; f < 8; ++f) {                    // double-angle
                const float sp = s[ch][f - 1], cp = c[ch][f - 1];
                s[ch][f] = 2.0f * sp * cp;
                c[ch][f] = fmaf(2.0f * cp, cp, -1.0f);
            }
        }

        float e[64];
#pragma unroll
        for (int k = 0; k < 64; ++k) e[k] = 0.0f;
        e[0] = xc[0]; e[1] = xc[1]; e[2] = xc[2];
#pragma unroll
        for (int ch = 0; ch < 3; ++ch)
#pragma unroll
            for (int f = 0; f < 8; ++f) {
                e[3  + ch * 8 + f] = s[ch][f];
                e[27 + ch * 8 + f] = c[ch][f];
            }

        const int row = lane & 31, rs = row & 15, g5 = lane >> 5;
#pragma unroll
        for (int t = 0; t < 8; ++t) {
            const int gr = 8 * g5 + t;
            float4v v = {e[4 * gr], e[4 * gr + 1], e[4 * gr + 2], e[4 * gr + 3]};
            *(float4v*)&hb[row * 64 + ((gr ^ rs) << 2)] = v;
        }
    }
    // no barrier: tile is wave-private; same-wave DS ops are ordered (HW-proven)

    mlp_layer<0, 4, true >(W0, b0, hb, nullptr, wbase, lane, n);
    mlp_layer<1, 4, true >(W1, b1, hb, nullptr, wbase, lane, n);
    mlp_layer<1, 4, true >(W2, b2, hb, nullptr, wbase, lane, n);
    mlp_layer<2, 1, false>(W3, b3, hb, out,     wbase, lane, n);
}

extern "C" void kernel_launch(void* const* d_in, const int* in_sizes, int n_in,
                              void* d_out, int out_size, void* d_ws, size_t ws_size,
                              hipStream_t stream)
{
    const float* x  = (const float*)d_in[0];
    const float* W0 = (const float*)d_in[1];
    const float* b0 = (const float*)d_in[2];
    const float* W1 = (const float*)d_in[3];
    const float* b1 = (const float*)d_in[4];
    const float* W2 = (const float*)d_in[5];
    const float* b2 = (const float*)d_in[6];
    const float* W3 = (const float*)d_in[7];
    const float* b3 = (const float*)d_in[8];
    float* out = (float*)d_out;

    const long long n = in_sizes[0] / 3;                   // 1<<20 points
    const int grid = (int)((n + 127) / 128);               // 32 pts/wave, 4 waves
    fused_mlp_r4<<<grid, 256, 0, stream>>>(x, W0, b0, W1, b1, W2, b2, W3, b3, out, n);
}

// Round 5
// 332.978 us; speedup vs baseline: 1.0397x; 1.0397x over previous
//
#include <hip/hip_runtime.h>
#include <cmath>

// Fused Fourier-MLP, single self-contained kernel.
// R5 = R4 with the ONE bug fixed: __launch_bounds__(256,4) forced VGPR=64 and
// caused massive scratch spills (WRITE_SIZE 568 MB vs 16 MB ideal, 346us).
// Plain __launch_bounds__(256) lets the allocator use ~112-130 VGPR, no spill;
// occupancy comes from the 8 KB/wave LDS tile (4 blocks/CU -> 16 waves/CU).
// Numerics (validated, absmax 0.015625): activations split f32 -> f16 hi+lo,
// weights rounded to f16; acc = Ah*Bh + Al*Bh, fp32 accum, bias as C-init.
// Per-wave private LDS tile [32][64] f32, XOR swizzle on 16B granules
// (phys = logical ^ (row&15)); 0 bank conflicts measured.
// Trig: sincosf(pi*x) seed + 7 double-angle steps per channel.

typedef _Float16 half8 __attribute__((ext_vector_type(8)));
typedef float float4v __attribute__((ext_vector_type(4)));

#define PI_F 3.14159265358979323846f

__device__ __forceinline__ float4v mfma16(half8 a, half8 b, float4v c) {
    return __builtin_amdgcn_mfma_f32_16x16x32_f16(a, b, c, 0, 0, 0);
}

// MODE 0: first layer, W row-stride 51, predicated k<51 (scalar loads, L1-hot)
// MODE 1: hidden 64x64 dense (vectorized float4 loads, L1-hot)
// MODE 2: last layer, W3 [4][64]: jch = l15 < 4 predicated, NT = 1, global out
template <int MODE, int NT, bool RELU>
__device__ __forceinline__ void mlp_layer(const float* __restrict__ W,
                                          const float* __restrict__ bias,
                                          float* __restrict__ hb,
                                          float* __restrict__ outp,
                                          long long wbase, int lane, long long n)
{
    const int l15 = lane & 15;
    const int g   = lane >> 4;

    // ---- A-phase: activations from LDS, split f32 -> f16 hi/lo.
    // Fragment mapping (HW-verified R2): slot j, group g, chunk c <-> k = 32c+8g+j.
    half8 Ah[2][2], Al[2][2];
#pragma unroll
    for (int mt = 0; mt < 2; ++mt) {
        const int row = 16 * mt + l15;
#pragma unroll
        for (int c = 0; c < 2; ++c) {
            const int gl = 8 * c + 2 * g;                  // logical 16B granule
            float4v r0 = *(const float4v*)&hb[row * 64 + ((gl ^ l15) << 2)];
            float4v r1 = *(const float4v*)&hb[row * 64 + (((gl + 1) ^ l15) << 2)];
#pragma unroll
            for (int j = 0; j < 4; ++j) {
                float v0 = r0[j]; _Float16 h0 = (_Float16)v0;
                Ah[mt][c][j] = h0; Al[mt][c][j] = (_Float16)(v0 - (float)h0);
                float v1 = r1[j]; _Float16 h1 = (_Float16)v1;
                Ah[mt][c][4 + j] = h1; Al[mt][c][4 + j] = (_Float16)(v1 - (float)h1);
            }
        }
    }

#pragma unroll
    for (int nt = 0; nt < NT; ++nt) {
        const int jch = 16 * nt + l15;
        float bj;
        if constexpr (MODE == 2) bj = (l15 < 4) ? bias[l15] : 0.0f;
        else                     bj = bias[jch];

        // ---- B-phase: weights -> f16 (hi only; lo term dropped, err ~1e-3)
        half8 Bh[2];
#pragma unroll
        for (int c = 0; c < 2; ++c) {
            if constexpr (MODE == 0) {
#pragma unroll
                for (int jj = 0; jj < 8; ++jj) {
                    const int k = 32 * c + 8 * g + jj;
                    const float w = (k < 51) ? W[jch * 51 + k] : 0.0f;
                    Bh[c][jj] = (_Float16)w;
                }
            } else if constexpr (MODE == 1) {
                const float4v* Wv = (const float4v*)(W + jch * 64 + 32 * c + 8 * g);
                float4v w0 = Wv[0], w1 = Wv[1];
#pragma unroll
                for (int jj = 0; jj < 4; ++jj) {
                    Bh[c][jj]     = (_Float16)w0[jj];
                    Bh[c][4 + jj] = (_Float16)w1[jj];
                }
            } else {                                        // MODE 2: W3 [4][64]
                if (l15 < 4) {
                    const float4v* Wv = (const float4v*)(W + l15 * 64 + 32 * c + 8 * g);
                    float4v w0 = Wv[0], w1 = Wv[1];
#pragma unroll
                    for (int jj = 0; jj < 4; ++jj) {
                        Bh[c][jj]     = (_Float16)w0[jj];
                        Bh[c][4 + jj] = (_Float16)w1[jj];
                    }
                } else {
#pragma unroll
                    for (int jj = 0; jj < 8; ++jj) Bh[c][jj] = (_Float16)0.0f;
                }
            }
        }

#pragma unroll
        for (int mt = 0; mt < 2; ++mt) {
            float4v acc = {bj, bj, bj, bj};
#pragma unroll
            for (int c = 0; c < 2; ++c) {
                acc = mfma16(Ah[mt][c], Bh[c], acc);
                acc = mfma16(Al[mt][c], Bh[c], acc);
            }
            // C-layout: col = l15, rows = 16mt + 4g + r  (HW-verified R2)
            if constexpr (MODE == 2) {
                if (l15 < 4) {
#pragma unroll
                    for (int r = 0; r < 4; ++r) {
                        long long p = wbase + 16 * mt + 4 * g + r;
                        if (p < n) outp[p * 4 + l15] = acc[r];
                    }
                }
            } else {
#pragma unroll
                for (int r = 0; r < 4; ++r) {
                    float v = acc[r];
                    if (RELU) v = fmaxf(v, 0.0f);
                    const int row = 16 * mt + 4 * g + r;
                    const int phys = (jch >> 2) ^ (row & 15);
                    hb[row * 64 + (phys << 2) + (jch & 3)] = v;
                }
            }
        }
    }
}

__global__ __launch_bounds__(256)
void fused_mlp_r5(const float* __restrict__ x,
                  const float* __restrict__ W0, const float* __restrict__ b0,
                  const float* __restrict__ W1, const float* __restrict__ b1,
                  const float* __restrict__ W2, const float* __restrict__ b2,
                  const float* __restrict__ W3, const float* __restrict__ b3,
                  float* __restrict__ out, long long n)
{
    __shared__ float hbuf[4][32 * 64];                     // 32 KB, 8 KB/wave
    const int tid  = threadIdx.x;
    const int wave = tid >> 6;
    const int lane = tid & 63;
    float* hb = hbuf[wave];

    const long long wbase = (long long)blockIdx.x * 128 + wave * 32;

    // ---- encoding: lane pair (l, l+32) both compute point (wbase + (l&31));
    //      group 0 writes granules 0..7 (cols 0..31), group 1 writes 8..15.
    {
        long long p = wbase + (lane & 31);
        if (p > n - 1) p = n - 1;
        const float xc[3] = {x[3 * p + 0], x[3 * p + 1], x[3 * p + 2]};

        float s[3][8], c[3][8];
#pragma unroll
        for (int ch = 0; ch < 3; ++ch) {
            sincosf(PI_F * xc[ch], &s[ch][0], &c[ch][0]);   // seed (arg <= pi)
#pragma unroll
            for (int f = 1; f < 8; ++f) {                    // double-angle
                const float sp = s[ch][f - 1], cp = c[ch][f - 1];
                s[ch][f] = 2.0f * sp * cp;
                c[ch][f] = fmaf(2.0f * cp, cp, -1.0f);
            }
        }

        float e[64];
#pragma unroll
        for (int k = 0; k < 64; ++k) e[k] = 0.0f;
        e[0] = xc[0]; e[1] = xc[1]; e[2] = xc[2];
#pragma unroll
        for (int ch = 0; ch < 3; ++ch)
#pragma unroll
            for (int f = 0; f < 8; ++f) {
                e[3  + ch * 8 + f] = s[ch][f];
                e[27 + ch * 8 + f] = c[ch][f];
            }

        const int row = lane & 31, rs = row & 15, g5 = lane >> 5;
#pragma unroll
        for (int t = 0; t < 8; ++t) {
            const int gr = 8 * g5 + t;
            float4v v = {e[4 * gr], e[4 * gr + 1], e[4 * gr + 2], e[4 * gr + 3]};
            *(float4v*)&hb[row * 64 + ((gr ^ rs) << 2)] = v;
        }
    }
    // no barrier: tile is wave-private; same-wave DS ops are ordered (HW-proven)

    mlp_layer<0, 4, true >(W0, b0, hb, nullptr, wbase, lane, n);
    mlp_layer<1, 4, true >(W1, b1, hb, nullptr, wbase, lane, n);
    mlp_layer<1, 4, true >(W2, b2, hb, nullptr, wbase, lane, n);
    mlp_layer<2, 1, false>(W3, b3, hb, out,     wbase, lane, n);
}

extern "C" void kernel_launch(void* const* d_in, const int* in_sizes, int n_in,
                              void* d_out, int out_size, void* d_ws, size_t ws_size,
                              hipStream_t stream)
{
    const float* x  = (const float*)d_in[0];
    const float* W0 = (const float*)d_in[1];
    const float* b0 = (const float*)d_in[2];
    const float* W1 = (const float*)d_in[3];
    const float* b1 = (const float*)d_in[4];
    const float* W2 = (const float*)d_in[5];
    const float* b2 = (const float*)d_in[6];
    const float* W3 = (const float*)d_in[7];
    const float* b3 = (const float*)d_in[8];
    float* out = (float*)d_out;

    const long long n = in_sizes[0] / 3;                   // 1<<20 points
    const int grid = (int)((n + 127) / 128);               // 32 pts/wave, 4 waves
    fused_mlp_r5<<<grid, 256, 0, stream>>>(x, W0, b0, W1, b1, W2, b2, W3, b3, out, n);
}

// Round 8
// 255.514 us; speedup vs baseline: 1.3549x; 1.3032x over previous
//
#include <hip/hip_runtime.h>
#include <cmath>

// Fused Fourier-MLP, single self-contained kernel.
// R8 = R6/R7 resubmitted verbatim (two GPU-acquisition timeouts; the fix is
// still unmeasured). R4/R5's 540 MB WRITE_SIZE / VGPR=60 was rule #20:
// encoding store used e[4*gr] with gr = 8*(lane>>5)+t — a RUNTIME index ->
// e[64] demoted to scratch (2.1M threads x 64 f32 = 537 MB writes, matches
// measured 540 MB). Fix: branch on half-wave so every e[] index is
// compile-time; each branch is 8 static-index ds_write_b128.
// Numerics (validated, absmax 0.015625): activations split f32 -> f16 hi+lo,
// weights rounded to f16; acc = Ah*Bh + Al*Bh, fp32 accum, bias as C-init.
// Per-wave private LDS tile [32][64] f32, XOR swizzle on 16B granules
// (phys = logical ^ (row&15)); 0 bank conflicts measured.
// Trig: sincosf(pi*x) seed + 7 double-angle steps per channel.

typedef _Float16 half8 __attribute__((ext_vector_type(8)));
typedef float float4v __attribute__((ext_vector_type(4)));

#define PI_F 3.14159265358979323846f

__device__ __forceinline__ float4v mfma16(half8 a, half8 b, float4v c) {
    return __builtin_amdgcn_mfma_f32_16x16x32_f16(a, b, c, 0, 0, 0);
}

// MODE 0: first layer, W row-stride 51, predicated k<51 (scalar loads, L1-hot)
// MODE 1: hidden 64x64 dense (vectorized float4 loads, L1-hot)
// MODE 2: last layer, W3 [4][64]: jch = l15 < 4 predicated, NT = 1, global out
template <int MODE, int NT, bool RELU>
__device__ __forceinline__ void mlp_layer(const float* __restrict__ W,
                                          const float* __restrict__ bias,
                                          float* __restrict__ hb,
                                          float* __restrict__ outp,
                                          long long wbase, int lane, long long n)
{
    const int l15 = lane & 15;
    const int g   = lane >> 4;

    // ---- A-phase: activations from LDS, split f32 -> f16 hi/lo.
    // Fragment mapping (HW-verified R2): slot j, group g, chunk c <-> k = 32c+8g+j.
    half8 Ah[2][2], Al[2][2];
#pragma unroll
    for (int mt = 0; mt < 2; ++mt) {
        const int row = 16 * mt + l15;
#pragma unroll
        for (int c = 0; c < 2; ++c) {
            const int gl = 8 * c + 2 * g;                  // logical 16B granule
            float4v r0 = *(const float4v*)&hb[row * 64 + ((gl ^ l15) << 2)];
            float4v r1 = *(const float4v*)&hb[row * 64 + (((gl + 1) ^ l15) << 2)];
#pragma unroll
            for (int j = 0; j < 4; ++j) {
                float v0 = r0[j]; _Float16 h0 = (_Float16)v0;
                Ah[mt][c][j] = h0; Al[mt][c][j] = (_Float16)(v0 - (float)h0);
                float v1 = r1[j]; _Float16 h1 = (_Float16)v1;
                Ah[mt][c][4 + j] = h1; Al[mt][c][4 + j] = (_Float16)(v1 - (float)h1);
            }
        }
    }

#pragma unroll
    for (int nt = 0; nt < NT; ++nt) {
        const int jch = 16 * nt + l15;
        float bj;
        if constexpr (MODE == 2) bj = (l15 < 4) ? bias[l15] : 0.0f;
        else                     bj = bias[jch];

        // ---- B-phase: weights -> f16 (hi only; lo term dropped, err ~1e-3)
        half8 Bh[2];
#pragma unroll
        for (int c = 0; c < 2; ++c) {
            if constexpr (MODE == 0) {
#pragma unroll
                for (int jj = 0; jj < 8; ++jj) {
                    const int k = 32 * c + 8 * g + jj;
                    const float w = (k < 51) ? W[jch * 51 + k] : 0.0f;
                    Bh[c][jj] = (_Float16)w;
                }
            } else if constexpr (MODE == 1) {
                const float4v* Wv = (const float4v*)(W + jch * 64 + 32 * c + 8 * g);
                float4v w0 = Wv[0], w1 = Wv[1];
#pragma unroll
                for (int jj = 0; jj < 4; ++jj) {
                    Bh[c][jj]     = (_Float16)w0[jj];
                    Bh[c][4 + jj] = (_Float16)w1[jj];
                }
            } else {                                        // MODE 2: W3 [4][64]
                if (l15 < 4) {
                    const float4v* Wv = (const float4v*)(W + l15 * 64 + 32 * c + 8 * g);
                    float4v w0 = Wv[0], w1 = Wv[1];
#pragma unroll
                    for (int jj = 0; jj < 4; ++jj) {
                        Bh[c][jj]     = (_Float16)w0[jj];
                        Bh[c][4 + jj] = (_Float16)w1[jj];
                    }
                } else {
#pragma unroll
                    for (int jj = 0; jj < 8; ++jj) Bh[c][jj] = (_Float16)0.0f;
                }
            }
        }

#pragma unroll
        for (int mt = 0; mt < 2; ++mt) {
            float4v acc = {bj, bj, bj, bj};
#pragma unroll
            for (int c = 0; c < 2; ++c) {
                acc = mfma16(Ah[mt][c], Bh[c], acc);
                acc = mfma16(Al[mt][c], Bh[c], acc);
            }
            // C-layout: col = l15, rows = 16mt + 4g + r  (HW-verified R2)
            if constexpr (MODE == 2) {
                if (l15 < 4) {
#pragma unroll
                    for (int r = 0; r < 4; ++r) {
                        long long p = wbase + 16 * mt + 4 * g + r;
                        if (p < n) outp[p * 4 + l15] = acc[r];
                    }
                }
            } else {
#pragma unroll
                for (int r = 0; r < 4; ++r) {
                    float v = acc[r];
                    if (RELU) v = fmaxf(v, 0.0f);
                    const int row = 16 * mt + 4 * g + r;
                    const int phys = (jch >> 2) ^ (row & 15);
                    hb[row * 64 + (phys << 2) + (jch & 3)] = v;
                }
            }
        }
    }
}

__global__ __launch_bounds__(256)
void fused_mlp_r8(const float* __restrict__ x,
                  const float* __restrict__ W0, const float* __restrict__ b0,
                  const float* __restrict__ W1, const float* __restrict__ b1,
                  const float* __restrict__ W2, const float* __restrict__ b2,
                  const float* __restrict__ W3, const float* __restrict__ b3,
                  float* __restrict__ out, long long n)
{
    __shared__ float hbuf[4][32 * 64];                     // 32 KB, 8 KB/wave
    const int tid  = threadIdx.x;
    const int wave = tid >> 6;
    const int lane = tid & 63;
    float* hb = hbuf[wave];

    const long long wbase = (long long)blockIdx.x * 128 + wave * 32;

    // ---- encoding: lane pair (l, l+32) both compute point (wbase + (l&31));
    //      half-wave 0 writes granules 0..7 (e[0..31]), half-wave 1 writes 8..15
    //      (e[32..63]). Branch keeps ALL e[] indices compile-time (rule #20).
    {
        long long p = wbase + (lane & 31);
        if (p > n - 1) p = n - 1;
        const float xc[3] = {x[3 * p + 0], x[3 * p + 1], x[3 * p + 2]};

        float s[3][8], c[3][8];
#pragma unroll
        for (int ch = 0; ch < 3; ++ch) {
            sincosf(PI_F * xc[ch], &s[ch][0], &c[ch][0]);   // seed (arg <= pi)
#pragma unroll
            for (int f = 1; f < 8; ++f) {                    // double-angle
                const float sp = s[ch][f - 1], cp = c[ch][f - 1];
                s[ch][f] = 2.0f * sp * cp;
                c[ch][f] = fmaf(2.0f * cp, cp, -1.0f);
            }
        }

        float e[64];
#pragma unroll
        for (int k = 0; k < 64; ++k) e[k] = 0.0f;
        e[0] = xc[0]; e[1] = xc[1]; e[2] = xc[2];
#pragma unroll
        for (int ch = 0; ch < 3; ++ch)
#pragma unroll
            for (int f = 0; f < 8; ++f) {
                e[3  + ch * 8 + f] = s[ch][f];
                e[27 + ch * 8 + f] = c[ch][f];
            }

        const int row = lane & 31, rs = row & 15;
        if (lane < 32) {
#pragma unroll
            for (int t = 0; t < 8; ++t) {                    // granules 0..7
                float4v v = {e[4 * t], e[4 * t + 1], e[4 * t + 2], e[4 * t + 3]};
                *(float4v*)&hb[row * 64 + ((t ^ rs) << 2)] = v;
            }
        } else {
#pragma unroll
            for (int t = 0; t < 8; ++t) {                    // granules 8..15
                float4v v = {e[32 + 4 * t], e[32 + 4 * t + 1],
                             e[32 + 4 * t + 2], e[32 + 4 * t + 3]};
                *(float4v*)&hb[row * 64 + (((8 + t) ^ rs) << 2)] = v;
            }
        }
    }
    // no barrier: tile is wave-private; same-wave DS ops are ordered (HW-proven)

    mlp_layer<0, 4, true >(W0, b0, hb, nullptr, wbase, lane, n);
    mlp_layer<1, 4, true >(W1, b1, hb, nullptr, wbase, lane, n);
    mlp_layer<1, 4, true >(W2, b2, hb, nullptr, wbase, lane, n);
    mlp_layer<2, 1, false>(W3, b3, hb, out,     wbase, lane, n);
}

extern "C" void kernel_launch(void* const* d_in, const int* in_sizes, int n_in,
                              void* d_out, int out_size, void* d_ws, size_t ws_size,
                              hipStream_t stream)
{
    const float* x  = (const float*)d_in[0];
    const float* W0 = (const float*)d_in[1];
    const float* b0 = (const float*)d_in[2];
    const float* W1 = (const float*)d_in[3];
    const float* b1 = (const float*)d_in[4];
    const float* W2 = (const float*)d_in[5];
    const float* b2 = (const float*)d_in[6];
    const float* W3 = (const float*)d_in[7];
    const float* b3 = (const float*)d_in[8];
    float* out = (float*)d_out;

    const long long n = in_sizes[0] / 3;                   // 1<<20 points
    const int grid = (int)((n + 127) / 128);               // 32 pts/wave, 4 waves
    fused_mlp_r8<<<grid, 256, 0, stream>>>(x, W0, b0, W1, b1, W2, b2, W3, b3, out, n);
}